// Round 4
// baseline (41.291 us; speedup 1.0000x reference)
//
#include <hip/hip_runtime.h>
#include <cfloat>

typedef unsigned long long ull;
typedef int v2i __attribute__((ext_vector_type(2)));

constexpr int BDIM = 256;
constexpr int NPTS = 8192;
constexpr int KSEL = 16;
constexpr int PD_  = 16;
constexpr int DIN  = 20;
constexpr int HID  = 128;
constexpr int DOUT = 256;
constexpr int ROWS_B = 4;

__device__ __forceinline__ ull mkkey(float d, int n) {
    // positive-float bits are order-monotone; low 32 bits = index (tie-break)
    return ((ull)__float_as_uint(d) << 32) | (unsigned int)n;
}
__device__ __forceinline__ ull umin64(ull a, ull b) { return a < b ? a : b; }

// --- wave-min butterfly steps: DPP (VALU) for xor1/2/4/8, ds_swizzle for
// --- xor16 (within 32-lane group), permlane32_swap (VALU) for the 32-split.
template<int CTRL>
__device__ __forceinline__ ull dppmin_u64(ull v) {
    const int lo = __builtin_amdgcn_mov_dpp((int)(unsigned)v,   CTRL, 0xF, 0xF, true);
    const int hi = __builtin_amdgcn_mov_dpp((int)(v >> 32),     CTRL, 0xF, 0xF, true);
    const ull o = ((ull)(unsigned)hi << 32) | (unsigned)lo;
    return umin64(v, o);
}
__device__ __forceinline__ ull swz16min_u64(ull v) {
    const int lo = __builtin_amdgcn_ds_swizzle((int)(unsigned)v, 0x401F); // xor16
    const int hi = __builtin_amdgcn_ds_swizzle((int)(v >> 32),   0x401F);
    const ull o = ((ull)(unsigned)hi << 32) | (unsigned)lo;
    return umin64(v, o);
}
__device__ __forceinline__ ull half32min_u64(ull v, int lane) {
#if __has_builtin(__builtin_amdgcn_permlane32_swap)
    v2i rl = __builtin_amdgcn_permlane32_swap((int)(unsigned)v, (int)(unsigned)v, false, false);
    v2i rh = __builtin_amdgcn_permlane32_swap((int)(v >> 32),   (int)(v >> 32),   false, false);
    const int lo = (lane < 32) ? rl[1] : rl[0];
    const int hi = (lane < 32) ? rh[1] : rh[0];
    const ull o = ((ull)(unsigned)hi << 32) | (unsigned)lo;
#else
    const int lo = __shfl_xor((int)(unsigned)v, 32, 64);
    const int hi = __shfl_xor((int)(v >> 32),   32, 64);
    const ull o = ((ull)(unsigned)hi << 32) | (unsigned)lo;
#endif
    return umin64(v, o);
}
__device__ __forceinline__ ull wavemin_u64(ull v, int lane) {
    v = dppmin_u64<0xB1>(v);    // quad_perm [1,0,3,2] : xor 1
    v = dppmin_u64<0x4E>(v);    // quad_perm [2,3,0,1] : xor 2
    v = dppmin_u64<0x124>(v);   // row_ror:4  -> min over 4-groups in row16
    v = dppmin_u64<0x128>(v);   // row_ror:8  -> full row16 min, every lane
    v = swz16min_u64(v);        // xor16 within 32-lane half
    v = half32min_u64(v, lane); // cross 32 halves
    return v;
}

// ---------------- Kernel A: distance + exact top-16 + feature vector --------
__global__ __launch_bounds__(BDIM, 4) void select_kernel(
    const float* __restrict__ lg,      // (2,)
    const float* __restrict__ coords,  // (B, N, 3)
    const float* __restrict__ params,  // (B, N, 16)
    float* __restrict__ xv)            // (B, 20) workspace
{
    __shared__ ull   wtop[4][KSEL];    // per-wave sorted top-16
    __shared__ int   sel[KSEL];
    __shared__ float nb_par[KSEL][PD_ + 1];
    __shared__ float nb_xy[KSEL][2];

    const int b    = blockIdx.x;
    const int tid  = threadIdx.x;
    const int lane = tid & 63;
    const int wid  = tid >> 6;
    const float lg0 = lg[0];
    const float lg1 = lg[1];

    // ---- Phase 1: distances for 32 points/thread, f32 registers ----
    const float4* c4 = reinterpret_cast<const float4*>(coords + (size_t)b * NPTS * 3);

    float dd[32];
    #pragma unroll
    for (int it = 0; it < 8; ++it) {
        const int g = it * BDIM + tid;
        const float4 qa = c4[3 * g + 0];
        const float4 qb = c4[3 * g + 1];
        const float4 qc = c4[3 * g + 2];
        const float px[4] = {qa.x, qa.w, qb.z, qc.y};
        const float py[4] = {qa.y, qb.x, qb.w, qc.z};
        #pragma unroll
        for (int j = 0; j < 4; ++j) {
            // match numpy rounding: sub, sub, mul, mul, add — no fma contraction
            const float t0 = __fsub_rn(lg0, px[j]);
            const float t1 = __fsub_rn(lg1, py[j]);
            dd[it * 4 + j] = __fadd_rn(__fmul_rn(t0, t0), __fmul_rn(t1, t1));
        }
    }
    // global point index of slot (g, j): n = (g<<10) + (tid<<2) + j

    // ---- per-thread group minima + thread min ----
    ull g8[8];
    #pragma unroll
    for (int g = 0; g < 8; ++g) {
        const int nb = (g << 10) + (tid << 2);
        const ull a = umin64(mkkey(dd[4*g+0], nb+0), mkkey(dd[4*g+1], nb+1));
        const ull c = umin64(mkkey(dd[4*g+2], nb+2), mkkey(dd[4*g+3], nb+3));
        g8[g] = umin64(a, c);
    }
    ull lkey;
    {
        const ull t0 = umin64(g8[0], g8[1]);
        const ull t1 = umin64(g8[2], g8[3]);
        const ull t2 = umin64(g8[4], g8[5]);
        const ull t3 = umin64(g8[6], g8[7]);
        lkey = umin64(umin64(t0, t1), umin64(t2, t3));
    }

    // ---- Phase 2: per-wave top-16 (wave-local, barrier-free rounds) ----
    unsigned int removed = 0u;
    for (int r = 0; r < KSEL; ++r) {
        const ull w = wavemin_u64(lkey, lane);   // full-wave min, all lanes
        if (lane == 0) wtop[wid][r] = w;
        const int wi = (int)(unsigned)w;         // winning point index in wave
        if (((wi >> 2) & 255) == tid) {          // owner removes & rebuilds
            const int gw = wi >> 10;
            removed |= 1u << ((gw << 2) | (wi & 3));
            #pragma unroll
            for (int g = 0; g < 8; ++g) {
                if (g == gw) {                   // static indexing only
                    const int nb = (g << 10) + (tid << 2);
                    const ull k0 = (removed & (1u << (4*g+0))) ? ~0ull : mkkey(dd[4*g+0], nb+0);
                    const ull k1 = (removed & (1u << (4*g+1))) ? ~0ull : mkkey(dd[4*g+1], nb+1);
                    const ull k2 = (removed & (1u << (4*g+2))) ? ~0ull : mkkey(dd[4*g+2], nb+2);
                    const ull k3 = (removed & (1u << (4*g+3))) ? ~0ull : mkkey(dd[4*g+3], nb+3);
                    g8[g] = umin64(umin64(k0, k1), umin64(k2, k3));
                }
            }
            const ull t0 = umin64(g8[0], g8[1]);
            const ull t1 = umin64(g8[2], g8[3]);
            const ull t2 = umin64(g8[4], g8[5]);
            const ull t3 = umin64(g8[6], g8[7]);
            lkey = umin64(umin64(t0, t1), umin64(t2, t3));
        }
    }
    __syncthreads();

    // ---- Phase 3: merge 4 sorted 16-lists (keys unique -> exact) ----
    if (tid == 0) {
        int p0 = 0, p1 = 0, p2 = 0, p3 = 0;
        for (int r = 0; r < KSEL; ++r) {
            const ull h0 = wtop[0][p0], h1 = wtop[1][p1];
            const ull h2 = wtop[2][p2], h3 = wtop[3][p3];
            const ull m = umin64(umin64(h0, h1), umin64(h2, h3));
            sel[r] = (int)(unsigned)m;
            if (m == h0) ++p0; else if (m == h1) ++p1;
            else if (m == h2) ++p2; else ++p3;
        }
    }
    __syncthreads();

    // ---- Phase 4: coalesced gather of neighbors, means -> xv row ----
    {
        const int k = tid >> 4, p = tid & 15;     // 256 threads = 16x16 cells
        nb_par[k][p] = params[((size_t)b * NPTS + sel[k]) * PD_ + p];
    }
    if (tid < 2 * KSEL) {
        const int k = tid >> 1, c = tid & 1;
        nb_xy[k][c] = coords[((size_t)b * NPTS + sel[k]) * 3 + c];
    }
    __syncthreads();
    if (tid < DIN) {
        float v;
        if (tid < 2) {
            v = lg[tid];
        } else if (tid < 4) {
            float s = 0.f;
            for (int k = 0; k < KSEL; ++k) s += nb_xy[k][tid - 2];
            v = s * (1.f / 16.f);
        } else {
            float s = 0.f;
            for (int k = 0; k < KSEL; ++k) s += nb_par[k][tid - 4];
            v = s * (1.f / 16.f);
        }
        xv[(size_t)b * DIN + tid] = v;
    }
}

// ---------------- Kernel B: MLP 20 -> 128 -> 128 -> 256, 4 rows/block ------
__global__ __launch_bounds__(BDIM) void mlp_kernel(
    const float* __restrict__ xv,
    const float* __restrict__ W1, const float* __restrict__ b1,
    const float* __restrict__ W2, const float* __restrict__ b2,
    const float* __restrict__ W3, const float* __restrict__ b3,
    float* __restrict__ out, int nrows)
{
    __shared__ float xls[ROWS_B][DIN];
    __shared__ float h1s[ROWS_B][HID];
    __shared__ float h2s[ROWS_B][HID];

    const int tid = threadIdx.x;
    const int r0  = blockIdx.x * ROWS_B;

    if (tid < ROWS_B * DIN) {
        const int r = tid / DIN, i = tid - r * DIN;
        xls[r][i] = (r0 + r < nrows) ? xv[(size_t)(r0 + r) * DIN + i] : 0.f;
    }
    __syncthreads();

    if (tid < HID) {
        float a0 = b1[tid], a1 = a0, a2 = a0, a3 = a0;
        #pragma unroll
        for (int i = 0; i < DIN; ++i) {
            const float w = W1[i * HID + tid];
            a0 = fmaf(xls[0][i], w, a0);
            a1 = fmaf(xls[1][i], w, a1);
            a2 = fmaf(xls[2][i], w, a2);
            a3 = fmaf(xls[3][i], w, a3);
        }
        h1s[0][tid] = fmaxf(a0, 0.f);
        h1s[1][tid] = fmaxf(a1, 0.f);
        h1s[2][tid] = fmaxf(a2, 0.f);
        h1s[3][tid] = fmaxf(a3, 0.f);
    }
    __syncthreads();

    if (tid < HID) {
        float a0 = b2[tid], a1 = a0, a2 = a0, a3 = a0;
        #pragma unroll 16
        for (int i = 0; i < HID; ++i) {
            const float w = W2[i * HID + tid];
            a0 = fmaf(h1s[0][i], w, a0);
            a1 = fmaf(h1s[1][i], w, a1);
            a2 = fmaf(h1s[2][i], w, a2);
            a3 = fmaf(h1s[3][i], w, a3);
        }
        h2s[0][tid] = fmaxf(a0, 0.f);
        h2s[1][tid] = fmaxf(a1, 0.f);
        h2s[2][tid] = fmaxf(a2, 0.f);
        h2s[3][tid] = fmaxf(a3, 0.f);
    }
    __syncthreads();

    {
        float a0 = b3[tid], a1 = a0, a2 = a0, a3 = a0;
        #pragma unroll 16
        for (int i = 0; i < HID; ++i) {
            const float w = W3[i * DOUT + tid];
            a0 = fmaf(h2s[0][i], w, a0);
            a1 = fmaf(h2s[1][i], w, a1);
            a2 = fmaf(h2s[2][i], w, a2);
            a3 = fmaf(h2s[3][i], w, a3);
        }
        if (r0 + 0 < nrows) out[(size_t)(r0 + 0) * DOUT + tid] = a0;
        if (r0 + 1 < nrows) out[(size_t)(r0 + 1) * DOUT + tid] = a1;
        if (r0 + 2 < nrows) out[(size_t)(r0 + 2) * DOUT + tid] = a2;
        if (r0 + 3 < nrows) out[(size_t)(r0 + 3) * DOUT + tid] = a3;
    }
}

extern "C" void kernel_launch(void* const* d_in, const int* in_sizes, int n_in,
                              void* d_out, int out_size, void* d_ws, size_t ws_size,
                              hipStream_t stream) {
    const float* lg     = (const float*)d_in[0];
    const float* coords = (const float*)d_in[1];
    const float* params = (const float*)d_in[2];
    const float* W1     = (const float*)d_in[3];
    const float* b1     = (const float*)d_in[4];
    const float* W2     = (const float*)d_in[5];
    const float* b2     = (const float*)d_in[6];
    const float* W3     = (const float*)d_in[7];
    const float* b3     = (const float*)d_in[8];
    float* out          = (float*)d_out;
    float* xv           = (float*)d_ws;          // (B, 20) f32 = 80 KB

    const int Brows = in_sizes[1] / (NPTS * 3);  // 1024
    select_kernel<<<dim3(Brows), dim3(BDIM), 0, stream>>>(lg, coords, params, xv);
    const int nB = (Brows + ROWS_B - 1) / ROWS_B;
    mlp_kernel<<<dim3(nB), dim3(BDIM), 0, stream>>>(xv, W1, b1, W2, b2, W3, b3,
                                                    out, Brows);
}

// Round 5
// 34.829 us; speedup vs baseline: 1.1855x; 1.1855x over previous
//
#include <hip/hip_runtime.h>
#include <cfloat>

typedef unsigned long long ull;
typedef int v2i __attribute__((ext_vector_type(2)));

constexpr int BDIM = 256;
constexpr int NPTS = 8192;
constexpr int KSEL = 16;
constexpr int PD_  = 16;
constexpr int DIN  = 20;
constexpr int HID  = 128;
constexpr int DOUT = 256;
constexpr int ROWS_B = 4;
constexpr int CAP  = 256;      // candidate capacity (E[cnt] ~ 20)

__device__ __forceinline__ ull mkkey(float d, int n) {
    // positive-float bits are order-monotone; low 32 bits = index (tie-break)
    return ((ull)__float_as_uint(d) << 32) | (unsigned int)n;
}
__device__ __forceinline__ ull umin64(ull a, ull b) { return a < b ? a : b; }
__device__ __forceinline__ ull umax64(ull a, ull b) { return a > b ? a : b; }

// ---------- f32 wave butterfly min (DPP + 1 ds_swizzle + permlane32) --------
template<int CTRL>
__device__ __forceinline__ float dppmin_f32(float v) {
    const int o = __builtin_amdgcn_mov_dpp(__float_as_int(v), CTRL, 0xF, 0xF, true);
    return fminf(v, __int_as_float(o));
}
__device__ __forceinline__ float swz16min_f32(float v) {
    const int o = __builtin_amdgcn_ds_swizzle(__float_as_int(v), 0x401F); // xor16
    return fminf(v, __int_as_float(o));
}
__device__ __forceinline__ float half32min_f32(float v, int lane) {
#if __has_builtin(__builtin_amdgcn_permlane32_swap)
    v2i r = __builtin_amdgcn_permlane32_swap(__float_as_int(v), __float_as_int(v), false, false);
    const int o = (lane < 32) ? r[1] : r[0];
#else
    const int o = __shfl_xor(__float_as_int(v), 32, 64);
#endif
    return fminf(v, __int_as_float(o));
}
__device__ __forceinline__ float wavemin_f32(float v, int lane) {
    v = dppmin_f32<0xB1>(v);    // quad_perm xor1
    v = dppmin_f32<0x4E>(v);    // quad_perm xor2
    v = dppmin_f32<0x124>(v);   // row_ror:4
    v = dppmin_f32<0x128>(v);   // row_ror:8
    v = swz16min_f32(v);        // xor16
    v = half32min_f32(v, lane); // cross-32
    return v;
}

// ---------- u64 wave butterfly min / max -----------------------------------
template<int CTRL>
__device__ __forceinline__ ull dppmov_u64(ull v) {
    const int lo = __builtin_amdgcn_mov_dpp((int)(unsigned)v, CTRL, 0xF, 0xF, true);
    const int hi = __builtin_amdgcn_mov_dpp((int)(v >> 32),   CTRL, 0xF, 0xF, true);
    return ((ull)(unsigned)hi << 32) | (unsigned)lo;
}
__device__ __forceinline__ ull swz16mov_u64(ull v) {
    const int lo = __builtin_amdgcn_ds_swizzle((int)(unsigned)v, 0x401F);
    const int hi = __builtin_amdgcn_ds_swizzle((int)(v >> 32),   0x401F);
    return ((ull)(unsigned)hi << 32) | (unsigned)lo;
}
__device__ __forceinline__ ull half32mov_u64(ull v, int lane) {
#if __has_builtin(__builtin_amdgcn_permlane32_swap)
    v2i rl = __builtin_amdgcn_permlane32_swap((int)(unsigned)v, (int)(unsigned)v, false, false);
    v2i rh = __builtin_amdgcn_permlane32_swap((int)(v >> 32),   (int)(v >> 32),   false, false);
    const int lo = (lane < 32) ? rl[1] : rl[0];
    const int hi = (lane < 32) ? rh[1] : rh[0];
    return ((ull)(unsigned)hi << 32) | (unsigned)lo;
#else
    const int lo = __shfl_xor((int)(unsigned)v, 32, 64);
    const int hi = __shfl_xor((int)(v >> 32),   32, 64);
    return ((ull)(unsigned)hi << 32) | (unsigned)lo;
#endif
}
__device__ __forceinline__ ull wavemin_u64(ull v, int lane) {
    v = umin64(v, dppmov_u64<0xB1>(v));
    v = umin64(v, dppmov_u64<0x4E>(v));
    v = umin64(v, dppmov_u64<0x124>(v));
    v = umin64(v, dppmov_u64<0x128>(v));
    v = umin64(v, swz16mov_u64(v));
    v = umin64(v, half32mov_u64(v, lane));
    return v;
}
__device__ __forceinline__ ull wavemax_u64(ull v, int lane) {
    v = umax64(v, dppmov_u64<0xB1>(v));
    v = umax64(v, dppmov_u64<0x4E>(v));
    v = umax64(v, dppmov_u64<0x124>(v));
    v = umax64(v, dppmov_u64<0x128>(v));
    v = umax64(v, swz16mov_u64(v));
    v = umax64(v, half32mov_u64(v, lane));
    return v;
}

// ---------------- Kernel A: distance + threshold top-16 + feature ----------
__global__ __launch_bounds__(BDIM, 4) void select_kernel(
    const float* __restrict__ lg,      // (2,)
    const float* __restrict__ coords,  // (B, N, 3)
    const float* __restrict__ params,  // (B, N, 16)
    float* __restrict__ xv)            // (B, 20) workspace
{
    __shared__ float dmin[BDIM];
    __shared__ ull   cand[CAP];
    __shared__ int   sel[KSEL];
    __shared__ int   lcnt, scnt;
    __shared__ float nb_par[KSEL][PD_ + 1];
    __shared__ float nb_xy[KSEL][2];

    const int b    = blockIdx.x;
    const int tid  = threadIdx.x;
    const int lane = tid & 63;
    const int wid  = tid >> 6;
    const float lg0 = lg[0];
    const float lg1 = lg[1];

    // ---- Phase 1: distances for 32 points/thread, f32 registers ----
    const float4* c4 = reinterpret_cast<const float4*>(coords + (size_t)b * NPTS * 3);

    float dd[32];
    #pragma unroll
    for (int it = 0; it < 8; ++it) {
        const int g = it * BDIM + tid;
        const float4 qa = c4[3 * g + 0];
        const float4 qb = c4[3 * g + 1];
        const float4 qc = c4[3 * g + 2];
        const float px[4] = {qa.x, qa.w, qb.z, qc.y};
        const float py[4] = {qa.y, qb.x, qb.w, qc.z};
        #pragma unroll
        for (int j = 0; j < 4; ++j) {
            // match numpy rounding: sub, sub, mul, mul, add — no fma contraction
            const float t0 = __fsub_rn(lg0, px[j]);
            const float t1 = __fsub_rn(lg1, py[j]);
            dd[it * 4 + j] = __fadd_rn(__fmul_rn(t0, t0), __fmul_rn(t1, t1));
        }
    }
    // global point index of slot (g, j): n = (g<<10) + (tid<<2) + j

    // ---- Phase 2a: per-thread min distance -> LDS ----
    float m;
    {
        float t[16];
        #pragma unroll
        for (int l = 0; l < 16; ++l) t[l] = fminf(dd[2 * l], dd[2 * l + 1]);
        #pragma unroll
        for (int s = 8; s > 0; s >>= 1)
            #pragma unroll
            for (int l = 0; l < 16; ++l) if (l < s) t[l] = fminf(t[l], t[l + s]);
        m = t[0];
    }
    dmin[tid] = m;
    if (tid == 0) { lcnt = 0; scnt = 0; }
    __syncthreads();

    // ---- Phase 2b: T = 16th-smallest of 256 thread-minima ----
    // (all 4 waves compute redundantly over identical data -> same T everywhere;
    //  tie-collapse can only RAISE T, which stays a safe superset threshold)
    float T;
    {
        float v0 = dmin[lane], v1 = dmin[lane + 64];
        float v2 = dmin[lane + 128], v3 = dmin[lane + 192];
        float loc = fminf(fminf(v0, v1), fminf(v2, v3));
        for (int r = 0; r < KSEL; ++r) {
            const float wmin = wavemin_f32(loc, lane);
            if (r == KSEL - 1) { T = wmin; break; }
            if (loc == wmin) {
                v0 = (v0 == wmin) ? FLT_MAX : v0;
                v1 = (v1 == wmin) ? FLT_MAX : v1;
                v2 = (v2 == wmin) ? FLT_MAX : v2;
                v3 = (v3 == wmin) ? FLT_MAX : v3;
                loc = fminf(fminf(v0, v1), fminf(v2, v3));
            }
        }
    }

    // ---- Phase 2c: gather candidates with d <= T (contains all top-16) ----
    #pragma unroll
    for (int g = 0; g < 8; ++g) {
        #pragma unroll
        for (int j = 0; j < 4; ++j) {
            const float d = dd[g * 4 + j];
            if (d <= T) {
                const int pos = atomicAdd(&lcnt, 1);
                if (pos < CAP) cand[pos] = mkkey(d, (g << 10) + (tid << 2) + j);
            }
        }
    }
    __syncthreads();

    // ---- Phase 2d: reduce candidates to exactly the 16 smallest keys ----
    if (wid == 0) {
        const int cnt = lcnt;
        const int cc  = cnt < CAP ? cnt : CAP;
        const int nrem = cnt - KSEL;
        if (nrem == 0) {
            if (lane < KSEL) sel[lane] = (int)(unsigned)cand[lane];
        } else if (nrem <= 15) {
            // remove the nrem largest (unique u64 keys -> exactly one owner/round)
            unsigned am = ((lane < cc) ? 1u : 0u) | ((lane + 64 < cc) ? 2u : 0u) |
                          ((lane + 128 < cc) ? 4u : 0u) | ((lane + 192 < cc) ? 8u : 0u);
            ull m0 = (am & 1) ? cand[lane]       : 0ull;
            ull m1 = (am & 2) ? cand[lane + 64]  : 0ull;
            ull m2 = (am & 4) ? cand[lane + 128] : 0ull;
            ull m3 = (am & 8) ? cand[lane + 192] : 0ull;
            ull loc = umax64(umax64(m0, m1), umax64(m2, m3));
            for (int r = 0; r < nrem; ++r) {
                const ull wmax = wavemax_u64(loc, lane);
                if (loc == wmax) {
                    if      (m0 == wmax) { m0 = 0ull; am &= ~1u; }
                    else if (m1 == wmax) { m1 = 0ull; am &= ~2u; }
                    else if (m2 == wmax) { m2 = 0ull; am &= ~4u; }
                    else                 { m3 = 0ull; am &= ~8u; }
                    loc = umax64(umax64(m0, m1), umax64(m2, m3));
                }
            }
            if (am & 1) { const int p = atomicAdd(&scnt, 1); sel[p] = (int)(unsigned)m0; }
            if (am & 2) { const int p = atomicAdd(&scnt, 1); sel[p] = (int)(unsigned)m1; }
            if (am & 4) { const int p = atomicAdd(&scnt, 1); sel[p] = (int)(unsigned)m2; }
            if (am & 8) { const int p = atomicAdd(&scnt, 1); sel[p] = (int)(unsigned)m3; }
        } else {
            // many candidates: extract 16 minima instead
            ull k0 = (lane < cc)       ? cand[lane]       : ~0ull;
            ull k1 = (lane + 64 < cc)  ? cand[lane + 64]  : ~0ull;
            ull k2 = (lane + 128 < cc) ? cand[lane + 128] : ~0ull;
            ull k3 = (lane + 192 < cc) ? cand[lane + 192] : ~0ull;
            ull loc = umin64(umin64(k0, k1), umin64(k2, k3));
            for (int r = 0; r < KSEL; ++r) {
                const ull wmin = wavemin_u64(loc, lane);
                if (lane == r) sel[r] = (int)(unsigned)wmin;
                if (loc == wmin) {
                    if      (k0 == wmin) k0 = ~0ull;
                    else if (k1 == wmin) k1 = ~0ull;
                    else if (k2 == wmin) k2 = ~0ull;
                    else                 k3 = ~0ull;
                    loc = umin64(umin64(k0, k1), umin64(k2, k3));
                }
            }
        }
    }
    __syncthreads();

    // ---- Phase 3: coalesced gather of neighbors, means -> xv row ----
    // (sel order is arbitrary; means are order-invariant)
    {
        const int k = tid >> 4, p = tid & 15;     // 256 threads = 16x16 cells
        nb_par[k][p] = params[((size_t)b * NPTS + sel[k]) * PD_ + p];
    }
    if (tid < 2 * KSEL) {
        const int k = tid >> 1, c = tid & 1;
        nb_xy[k][c] = coords[((size_t)b * NPTS + sel[k]) * 3 + c];
    }
    __syncthreads();
    if (tid < DIN) {
        float v;
        if (tid < 2) {
            v = lg[tid];
        } else if (tid < 4) {
            float s = 0.f;
            for (int k = 0; k < KSEL; ++k) s += nb_xy[k][tid - 2];
            v = s * (1.f / 16.f);
        } else {
            float s = 0.f;
            for (int k = 0; k < KSEL; ++k) s += nb_par[k][tid - 4];
            v = s * (1.f / 16.f);
        }
        xv[(size_t)b * DIN + tid] = v;
    }
}

// ---------------- Kernel B: MLP 20 -> 128 -> 128 -> 256, 4 rows/block ------
__global__ __launch_bounds__(BDIM) void mlp_kernel(
    const float* __restrict__ xv,
    const float* __restrict__ W1, const float* __restrict__ b1,
    const float* __restrict__ W2, const float* __restrict__ b2,
    const float* __restrict__ W3, const float* __restrict__ b3,
    float* __restrict__ out, int nrows)
{
    __shared__ float xls[ROWS_B][DIN];
    __shared__ float h1s[ROWS_B][HID];
    __shared__ float h2s[ROWS_B][HID];

    const int tid = threadIdx.x;
    const int r0  = blockIdx.x * ROWS_B;

    if (tid < ROWS_B * DIN) {
        const int r = tid / DIN, i = tid - r * DIN;
        xls[r][i] = (r0 + r < nrows) ? xv[(size_t)(r0 + r) * DIN + i] : 0.f;
    }
    __syncthreads();

    if (tid < HID) {
        float a0 = b1[tid], a1 = a0, a2 = a0, a3 = a0;
        #pragma unroll
        for (int i = 0; i < DIN; ++i) {
            const float w = W1[i * HID + tid];
            a0 = fmaf(xls[0][i], w, a0);
            a1 = fmaf(xls[1][i], w, a1);
            a2 = fmaf(xls[2][i], w, a2);
            a3 = fmaf(xls[3][i], w, a3);
        }
        h1s[0][tid] = fmaxf(a0, 0.f);
        h1s[1][tid] = fmaxf(a1, 0.f);
        h1s[2][tid] = fmaxf(a2, 0.f);
        h1s[3][tid] = fmaxf(a3, 0.f);
    }
    __syncthreads();

    if (tid < HID) {
        float a0 = b2[tid], a1 = a0, a2 = a0, a3 = a0;
        #pragma unroll 16
        for (int i = 0; i < HID; ++i) {
            const float w = W2[i * HID + tid];
            a0 = fmaf(h1s[0][i], w, a0);
            a1 = fmaf(h1s[1][i], w, a1);
            a2 = fmaf(h1s[2][i], w, a2);
            a3 = fmaf(h1s[3][i], w, a3);
        }
        h2s[0][tid] = fmaxf(a0, 0.f);
        h2s[1][tid] = fmaxf(a1, 0.f);
        h2s[2][tid] = fmaxf(a2, 0.f);
        h2s[3][tid] = fmaxf(a3, 0.f);
    }
    __syncthreads();

    {
        float a0 = b3[tid], a1 = a0, a2 = a0, a3 = a0;
        #pragma unroll 16
        for (int i = 0; i < HID; ++i) {
            const float w = W3[i * DOUT + tid];
            a0 = fmaf(h2s[0][i], w, a0);
            a1 = fmaf(h2s[1][i], w, a1);
            a2 = fmaf(h2s[2][i], w, a2);
            a3 = fmaf(h2s[3][i], w, a3);
        }
        if (r0 + 0 < nrows) out[(size_t)(r0 + 0) * DOUT + tid] = a0;
        if (r0 + 1 < nrows) out[(size_t)(r0 + 1) * DOUT + tid] = a1;
        if (r0 + 2 < nrows) out[(size_t)(r0 + 2) * DOUT + tid] = a2;
        if (r0 + 3 < nrows) out[(size_t)(r0 + 3) * DOUT + tid] = a3;
    }
}

extern "C" void kernel_launch(void* const* d_in, const int* in_sizes, int n_in,
                              void* d_out, int out_size, void* d_ws, size_t ws_size,
                              hipStream_t stream) {
    const float* lg     = (const float*)d_in[0];
    const float* coords = (const float*)d_in[1];
    const float* params = (const float*)d_in[2];
    const float* W1     = (const float*)d_in[3];
    const float* b1     = (const float*)d_in[4];
    const float* W2     = (const float*)d_in[5];
    const float* b2     = (const float*)d_in[6];
    const float* W3     = (const float*)d_in[7];
    const float* b3     = (const float*)d_in[8];
    float* out          = (float*)d_out;
    float* xv           = (float*)d_ws;          // (B, 20) f32 = 80 KB

    const int Brows = in_sizes[1] / (NPTS * 3);  // 1024
    select_kernel<<<dim3(Brows), dim3(BDIM), 0, stream>>>(lg, coords, params, xv);
    const int nB = (Brows + ROWS_B - 1) / ROWS_B;
    mlp_kernel<<<dim3(nB), dim3(BDIM), 0, stream>>>(xv, W1, b1, W2, b2, W3, b3,
                                                    out, Brows);
}

// Round 6
// 33.685 us; speedup vs baseline: 1.2258x; 1.0340x over previous
//
#include <hip/hip_runtime.h>
#include <cfloat>

typedef unsigned long long ull;
typedef int v2i __attribute__((ext_vector_type(2)));

constexpr int BDIM = 256;
constexpr int NPTS = 8192;
constexpr int QPTS = 2048;     // points per quarter-block
constexpr int KSEL = 16;
constexpr int PD_  = 16;
constexpr int DIN  = 20;
constexpr int HID  = 128;
constexpr int DOUT = 256;
constexpr int ROWS_B = 4;
constexpr int CAP  = 256;      // candidate capacity (E[cnt] ~ 40)

__device__ __forceinline__ ull mkkey(float d, int n) {
    // positive-float bits are order-monotone; low 32 bits = index (tie-break)
    return ((ull)__float_as_uint(d) << 32) | (unsigned int)n;
}

// ---------- f32 wave butterfly min (DPP + 1 ds_swizzle + permlane32) --------
template<int CTRL>
__device__ __forceinline__ float dppmin_f32(float v) {
    const int o = __builtin_amdgcn_mov_dpp(__float_as_int(v), CTRL, 0xF, 0xF, true);
    return fminf(v, __int_as_float(o));
}
__device__ __forceinline__ float swz16min_f32(float v) {
    const int o = __builtin_amdgcn_ds_swizzle(__float_as_int(v), 0x401F); // xor16
    return fminf(v, __int_as_float(o));
}
__device__ __forceinline__ float half32min_f32(float v, int lane) {
#if __has_builtin(__builtin_amdgcn_permlane32_swap)
    v2i r = __builtin_amdgcn_permlane32_swap(__float_as_int(v), __float_as_int(v), false, false);
    const int o = (lane < 32) ? r[1] : r[0];
#else
    const int o = __shfl_xor(__float_as_int(v), 32, 64);
#endif
    return fminf(v, __int_as_float(o));
}
__device__ __forceinline__ float wavemin_f32(float v, int lane) {
    v = dppmin_f32<0xB1>(v);    // quad_perm xor1
    v = dppmin_f32<0x4E>(v);    // quad_perm xor2
    v = dppmin_f32<0x124>(v);   // row_ror:4
    v = dppmin_f32<0x128>(v);   // row_ror:8
    v = swz16min_f32(v);        // xor16
    v = half32min_f32(v, lane); // cross-32
    return v;
}

// ------ Kernel A: per-quarter distances + exact quarter-top-16 keys --------
__global__ __launch_bounds__(BDIM, 8) void select_kernel(
    const float* __restrict__ lg,      // (2,)
    const float* __restrict__ coords,  // (B, N, 3)
    ull* __restrict__ keys)            // (B, 4, 16) u64 workspace
{
    __shared__ float twave[4];
    __shared__ ull   cand[CAP];
    __shared__ int   ccnt;

    const int blk  = blockIdx.x;
    const int row  = blk >> 2;
    const int q    = blk & 3;
    const int tid  = threadIdx.x;
    const int lane = tid & 63;
    const int wid  = tid >> 6;
    const float lg0 = lg[0];
    const float lg1 = lg[1];

    if (tid == 0) ccnt = 0;

    // ---- distances: 8 points/thread (2 float4-triples) ----
    const float4* c4 = reinterpret_cast<const float4*>(coords)
                       + (size_t)row * (NPTS * 3 / 4) + q * (QPTS * 3 / 4);
    float dd[8];
    #pragma unroll
    for (int it = 0; it < 2; ++it) {
        const int g = it * BDIM + tid;
        const float4 qa = c4[3 * g + 0];
        const float4 qb = c4[3 * g + 1];
        const float4 qc = c4[3 * g + 2];
        const float px[4] = {qa.x, qa.w, qb.z, qc.y};
        const float py[4] = {qa.y, qb.x, qb.w, qc.z};
        #pragma unroll
        for (int j = 0; j < 4; ++j) {
            // match numpy rounding: sub, sub, mul, mul, add — no fma contraction
            const float t0 = __fsub_rn(lg0, px[j]);
            const float t1 = __fsub_rn(lg1, py[j]);
            dd[it * 4 + j] = __fadd_rn(__fmul_rn(t0, t0), __fmul_rn(t1, t1));
        }
    }
    // local point index of slot (it,j): (it<<10) + (tid<<2) + j; global-in-row: + q*QPTS

    // ---- thread min ----
    float m;
    {
        const float a = fminf(fminf(dd[0], dd[1]), fminf(dd[2], dd[3]));
        const float b = fminf(fminf(dd[4], dd[5]), fminf(dd[6], dd[7]));
        m = fminf(a, b);
    }

    // ---- per-wave 4th-smallest thread-min; T = max over waves ----
    // (each wave then has >=4 thread-mins <= T -> >=16 points <= T block-wide;
    //  tie-collapse only raises T = safe superset)
    float tw;
    {
        float loc = m;
        #pragma unroll
        for (int r = 0; r < 4; ++r) {
            const float wmin = wavemin_f32(loc, lane);
            if (r == 3) { tw = wmin; break; }
            if (loc == wmin) loc = FLT_MAX;
        }
    }
    if (lane == 0) twave[wid] = tw;
    __syncthreads();
    const float T = fmaxf(fmaxf(twave[0], twave[1]), fmaxf(twave[2], twave[3]));

    // ---- candidates with d <= T (contains all quarter-top-16) ----
    #pragma unroll
    for (int it = 0; it < 2; ++it) {
        #pragma unroll
        for (int j = 0; j < 4; ++j) {
            const float d = dd[it * 4 + j];
            if (d <= T) {
                const int pos = atomicAdd(&ccnt, 1);
                if (pos < CAP)
                    cand[pos] = mkkey(d, (q << 11) + (it << 10) + (tid << 2) + j);
            }
        }
    }
    __syncthreads();

    // ---- exact quarter-top-16 by rank (unique keys -> rank is exact) ----
    if (wid == 0) {
        int cc = ccnt; if (cc > CAP) cc = CAP;
        for (int s = lane; s < cc; s += 64) {
            const ull k = cand[s];
            int rank = 0;
            for (int j = 0; j < cc; ++j) rank += (cand[j] < k);
            if (rank < KSEL) keys[(size_t)row * 64 + q * 16 + rank] = k;
        }
    }
}

// ------ Kernel B: merge 4x16 keys, gather, feature, MLP (4 rows/block) -----
__global__ __launch_bounds__(BDIM) void mlp_kernel(
    const float* __restrict__ lg,
    const float* __restrict__ coords,
    const float* __restrict__ params,
    const ull* __restrict__ keys,
    const float* __restrict__ W1, const float* __restrict__ b1,
    const float* __restrict__ W2, const float* __restrict__ b2,
    const float* __restrict__ W3, const float* __restrict__ b3,
    float* __restrict__ out, int nrows)
{
    __shared__ ull   wkeys[ROWS_B][64];
    __shared__ int   selb[ROWS_B][KSEL];
    __shared__ float pbuf[ROWS_B][KSEL][PD_];
    __shared__ float cbuf[ROWS_B][KSEL][2];
    __shared__ float xls[ROWS_B][DIN];
    __shared__ float h1s[ROWS_B][HID];
    __shared__ float h2s[ROWS_B][HID];

    const int tid  = threadIdx.x;
    const int lane = tid & 63;
    const int w    = tid >> 6;
    const int r0   = blockIdx.x * ROWS_B;
    const int row  = r0 + w;

    // ---- merge: exact top-16 of the row's 64 quarter keys (rank trick) ----
    const ull myk = keys[(size_t)row * 64 + lane];
    wkeys[w][lane] = myk;
    __syncthreads();
    {
        int rank = 0;
        #pragma unroll 8
        for (int j = 0; j < 64; ++j) rank += (wkeys[w][j] < myk);
        if (rank < KSEL) selb[w][rank] = (int)(unsigned)myk;  // argsort order
    }
    __syncthreads();

    // ---- gather neighbor rows (coalesced float4 for params) ----
    {
        const int k = lane >> 2, c = lane & 3;
        const float4 p4 = *reinterpret_cast<const float4*>(
            &params[((size_t)row * NPTS + selb[w][k]) * PD_ + 4 * c]);
        *reinterpret_cast<float4*>(&pbuf[w][k][4 * c]) = p4;
    }
    if (lane < 32) {
        const int k = lane >> 1, c = lane & 1;
        cbuf[w][k][c] = coords[((size_t)row * NPTS + selb[w][k]) * 3 + c];
    }
    __syncthreads();

    // ---- feature vector (means in argsort order, /16 exact) ----
    if (lane < DIN) {
        float v;
        if (lane < 2) {
            v = lg[lane];
        } else if (lane < 4) {
            float s = 0.f;
            for (int k = 0; k < KSEL; ++k) s += cbuf[w][k][lane - 2];
            v = s * (1.f / 16.f);
        } else {
            float s = 0.f;
            for (int k = 0; k < KSEL; ++k) s += pbuf[w][k][lane - 4];
            v = s * (1.f / 16.f);
        }
        xls[w][lane] = v;
    }
    __syncthreads();

    // ---- MLP 20 -> 128 -> 128 -> 256 (weights L2-resident) ----
    if (tid < HID) {
        float a0 = b1[tid], a1 = a0, a2 = a0, a3 = a0;
        #pragma unroll
        for (int i = 0; i < DIN; ++i) {
            const float wv = W1[i * HID + tid];
            a0 = fmaf(xls[0][i], wv, a0);
            a1 = fmaf(xls[1][i], wv, a1);
            a2 = fmaf(xls[2][i], wv, a2);
            a3 = fmaf(xls[3][i], wv, a3);
        }
        h1s[0][tid] = fmaxf(a0, 0.f);
        h1s[1][tid] = fmaxf(a1, 0.f);
        h1s[2][tid] = fmaxf(a2, 0.f);
        h1s[3][tid] = fmaxf(a3, 0.f);
    }
    __syncthreads();

    if (tid < HID) {
        float a0 = b2[tid], a1 = a0, a2 = a0, a3 = a0;
        #pragma unroll 16
        for (int i = 0; i < HID; ++i) {
            const float wv = W2[i * HID + tid];
            a0 = fmaf(h1s[0][i], wv, a0);
            a1 = fmaf(h1s[1][i], wv, a1);
            a2 = fmaf(h1s[2][i], wv, a2);
            a3 = fmaf(h1s[3][i], wv, a3);
        }
        h2s[0][tid] = fmaxf(a0, 0.f);
        h2s[1][tid] = fmaxf(a1, 0.f);
        h2s[2][tid] = fmaxf(a2, 0.f);
        h2s[3][tid] = fmaxf(a3, 0.f);
    }
    __syncthreads();

    {
        float a0 = b3[tid], a1 = a0, a2 = a0, a3 = a0;
        #pragma unroll 16
        for (int i = 0; i < HID; ++i) {
            const float wv = W3[i * DOUT + tid];
            a0 = fmaf(h2s[0][i], wv, a0);
            a1 = fmaf(h2s[1][i], wv, a1);
            a2 = fmaf(h2s[2][i], wv, a2);
            a3 = fmaf(h2s[3][i], wv, a3);
        }
        if (r0 + 0 < nrows) out[(size_t)(r0 + 0) * DOUT + tid] = a0;
        if (r0 + 1 < nrows) out[(size_t)(r0 + 1) * DOUT + tid] = a1;
        if (r0 + 2 < nrows) out[(size_t)(r0 + 2) * DOUT + tid] = a2;
        if (r0 + 3 < nrows) out[(size_t)(r0 + 3) * DOUT + tid] = a3;
    }
}

extern "C" void kernel_launch(void* const* d_in, const int* in_sizes, int n_in,
                              void* d_out, int out_size, void* d_ws, size_t ws_size,
                              hipStream_t stream) {
    const float* lg     = (const float*)d_in[0];
    const float* coords = (const float*)d_in[1];
    const float* params = (const float*)d_in[2];
    const float* W1     = (const float*)d_in[3];
    const float* b1     = (const float*)d_in[4];
    const float* W2     = (const float*)d_in[5];
    const float* b2     = (const float*)d_in[6];
    const float* W3     = (const float*)d_in[7];
    const float* b3     = (const float*)d_in[8];
    float* out          = (float*)d_out;
    ull*   keys         = (ull*)d_ws;            // (B, 4, 16) u64 = 512 KB

    const int Brows = in_sizes[1] / (NPTS * 3);  // 1024
    select_kernel<<<dim3(Brows * 4), dim3(BDIM), 0, stream>>>(lg, coords, keys);
    mlp_kernel<<<dim3(Brows / ROWS_B), dim3(BDIM), 0, stream>>>(
        lg, coords, params, keys, W1, b1, W2, b2, W3, b3, out, Brows);
}